// Round 7
// baseline (5409.536 us; speedup 1.0000x reference)
//
#include <hip/hip_runtime.h>
#include <math.h>

#define BN_EPS 1e-3f

typedef unsigned short ushort;
typedef unsigned int uint;
typedef __attribute__((ext_vector_type(8))) short bf16x8;
typedef __attribute__((ext_vector_type(4))) float f32x4;

__device__ __forceinline__ float hsig(float x) {
    return fminf(fmaxf(0.2f * x + 0.5f, 0.f), 1.f);
}
__device__ __forceinline__ ushort f2bf(float f) {
    uint u = __float_as_uint(f);
    u += 0x7fffu + ((u >> 16) & 1u);   // RNE
    return (ushort)(u >> 16);
}

// async global->LDS DMA, 16B/lane; LDS dest = wave-uniform base + lane*16;
// global src per-lane. aux=1 (sc0): L1-coherent path.
__device__ __forceinline__ void gld_lds16(const void* g, void* l) {
    __builtin_amdgcn_global_load_lds(
        (const __attribute__((address_space(1))) void*)g,
        (__attribute__((address_space(3))) void*)l, 16, 0, 1);
}

#define NB 512   // 2 blocks/CU on 256 CUs -> guaranteed co-resident

__device__ __forceinline__ void spin_until(uint* p, uint target) {
    int g = 0;
    while (__hip_atomic_load(p, __ATOMIC_RELAXED, __HIP_MEMORY_SCOPE_AGENT) < target) {
        __builtin_amdgcn_s_sleep(2);
        if (++g > (1 << 22)) break;   // degrade to wrong-answer, not hang
    }
}

// Device barrier with ELECTED per-XCD cache maintenance (R5 semantics, 1/64 cost):
//  flavor 0: arrive+spin only.
//  flavor 1: + elected block per XCD does release (buffer_wbl2) then signals.
//  flavor 2: + elected also does acquire (buffer_inv) before signaling.
// All blocks wait until all nxcd electeds signaled -> every XCD flushed/inv'd.
// R5 did wbl2+inv on ALL 512 blocks/barrier (64 serialized invs per XCD) ->
// ~130us/barrier. Here: exactly one per XCD.
__device__ __forceinline__ void gbar(uint* full, uint* invdone,
                                     uint epF, uint epI,
                                     uint elected, uint nxcd, int flavor)
{
    __syncthreads();                       // all stores retired to L2
    if (threadIdx.x == 0) {
        __hip_atomic_fetch_add(full, 1u, __ATOMIC_RELAXED, __HIP_MEMORY_SCOPE_AGENT);
        spin_until(full, epF * NB);        // all blocks' stores are in their L2s
        if (flavor) {
            if (elected) {
                // wbl2: flush this XCD's dirty set to IF
                __hip_atomic_fetch_add(full, 0u, __ATOMIC_RELEASE, __HIP_MEMORY_SCOPE_AGENT);
                if (flavor == 2)           // buffer_inv: drop stale clean lines
                    (void)__hip_atomic_load(full, __ATOMIC_ACQUIRE, __HIP_MEMORY_SCOPE_AGENT);
                asm volatile("s_waitcnt vmcnt(0) lgkmcnt(0)" ::: "memory");
                __hip_atomic_fetch_add(invdone, 1u, __ATOMIC_RELAXED, __HIP_MEMORY_SCOPE_AGENT);
            }
            spin_until(invdone, epI * nxcd);
        }
    }
    asm volatile("" ::: "memory");
    __syncthreads();
}

// ---------------------------------------------------------------------------
// pack (device fn): fp32 weights [3,Cin,4F]+[3,F,4F] -> bf16 fragment order.
// wp is write-once; published by the flavor-1 barrier after phase 0.
// ---------------------------------------------------------------------------
__device__ void pack_dev(char* slab_, const float* __restrict__ Wx, int Cin,
                         const float* __restrict__ Wh, int F,
                         uint4* __restrict__ wp, int S0, int S,
                         int nblk, int step)
{
    ushort (*Wt)[136] = (ushort (*)[136])slab_;
    const int tid = threadIdx.x;
    const int N4 = 4 * F;

    for (int idx = tid; idx < 32 * 128; idx += 256) {
        int kk = idx >> 7, c = idx & 127;
        int gate = c >> 5, fl = c & 31;
        int n = gate * F + nblk * 32 + fl;
        float v = 0.f;
        if (step < S0) {
            int ka = step * 32 + kk;
            if (ka < 3 * Cin) v = Wx[(long)ka * N4 + n];
        } else {
            int ka = (step - S0) * 32 + kk;
            v = Wh[(long)ka * N4 + n];
        }
        Wt[kk][c] = f2bf(v);
    }
    __syncthreads();

    for (int s = tid; s < 512; s += 256) {
        int colgrp = s >> 6, qq = (s >> 4) & 3, rr = s & 15;
        int gate = colgrp >> 1, wn = colgrp & 1;
        int c = gate * 32 + wn * 16 + rr;
        ushort tmp[8];
#pragma unroll
        for (int j = 0; j < 8; ++j) tmp[j] = Wt[qq * 8 + j][c];
        wp[(long)(nblk * S + step) * 512 + s] = *(const uint4*)tmp;
    }
}

// ---------------------------------------------------------------------------
// One gate tile. A slab staged ONCE per interval via global_load_lds DMA:
//  - linear LDS slot `la` holds element (ri, bo_lin ^ swz) -> per-lane global
//    source is pre-swizzled, LDS dest is lane-linear (rule #21 pattern).
//  - halo/OOB/im2col lanes redirect their SOURCE to a 64B zero buffer (R1-
//    proven); im2col x-region is overwritten after vmcnt(0).
//  - DMA path avoids both the inline-asm register hazard and vL1 staleness.
// B weights: plain cached loads, 2-deep rotation (read-only data).
// SWM: swizzle mask; L1 layer uses 3 (RS=192 is only 64-aligned, so bit-6
// swizzle would escape the row and break the slot inversion).
// c-state lives in VGPRs across the whole sequence.
// ---------------------------------------------------------------------------
template<int C0A, int S0, int S, int F, int NFLOG, int CIN1, int SWM>
__device__ void do_tile(char* slab, const ushort* __restrict__ zbuf,
        int tile, int L, const void* a0, long a0_bs,
        const ushort* __restrict__ h_old, ushort* __restrict__ h_new,
        const uint4* __restrict__ wp, const float* __restrict__ bias,
        void* bn_out, long bn_bs, int bnf32,
        const float* bn_g, const float* bn_b, const float* bn_m, const float* bn_v,
        f32x4* cst)
{
    __syncthreads();   // prior users of slab (this block) are done

    const int tid = threadIdx.x;
    const int lane = tid & 63;
    const int wave = tid >> 6;
    const int wn = wave & 1, wm = wave >> 1;
    const int q = lane >> 4, r = lane & 15;
    const int fblk = tile & ((1 << NFLOG) - 1);
    const int rest = tile >> NFLOG;
    const int lblk = rest & 1;
    const int b = rest >> 1;
    const int f0 = fblk * 32;
    const int l0 = lblk * 64;
    constexpr int c0shift = 31 - __builtin_clz(C0A);
    constexpr int cFshift = 31 - __builtin_clz(F);
    constexpr int RS = (C0A + F) * 2;       // bytes per slab row
    constexpr int NCH = RS >> 4;            // 16B chunks per row
    constexpr int TOT = 66 * NCH;
    constexpr int NIT = (TOT + 255) >> 8;
    constexpr int c0bytes = C0A * 2;

    // ---- B: direct global->reg fragment loads (cached), double-buffered ----
    const uint4* wpB = wp + (long)fblk * S * 512 + wn * 64 + lane;
    bf16x8 bA[4], bB[4];
    auto loadB = [&](int step, bf16x8* bv) {
#pragma unroll
        for (int g = 0; g < 4; ++g)
            bv[g] = *(const bf16x8*)(wpB + (long)step * 512 + g * 128);
    };
    loadB(0, bA);   // in flight under slab staging

    // ---- stage A slab via DMA (1 inst/wave/iter, pre-swizzled sources) ----
    {
        const ushort* a0b = (const ushort*)a0 + (long)b * a0_bs;
        const ushort* hb  = h_old + (long)b * L * F;
        const int wbase = tid & ~63;
#pragma unroll
        for (int it = 0; it < NIT; ++it) {
            const int slot = it * 256 + tid;
            const int ri = slot / NCH;
            const int bo_lin = (slot - ri * NCH) * 16;
            const int boff = bo_lin ^ ((ri & SWM) << 4);   // element coords
            const int l = l0 - 1 + ri;
            const void* src;
            if (ri >= 66 || (unsigned)l >= (unsigned)L ||
                (CIN1 && boff < c0bytes))
                src = (const void*)zbuf;
            else if (boff >= c0bytes)
                src = (const void*)(hb + (long)l * F + ((boff - c0bytes) >> 1));
            else
                src = (const void*)(a0b + (long)l * C0A + (boff >> 1));
            gld_lds16(src, slab + (it * 256 + wbase) * 16);
        }
        asm volatile("s_waitcnt vmcnt(0)" ::: "memory");
    }
    // im2col x-region (L1): overwrite the DMA'd zeros with real taps
    if (CIN1) {
        const float* xb = (const float*)a0 + (long)b * a0_bs;
        for (int s = tid; s < 66 * 4; s += 256) {
            int ri2 = s >> 2, co = s & 3;
            uint4 v = {0u, 0u, 0u, 0u};
            if (co == 0) {
                ushort t[8] = {0, 0, 0, 0, 0, 0, 0, 0};
#pragma unroll
                for (int j = 0; j < 3; ++j) {
                    int l = l0 - 1 + ri2 + j;
                    if (l >= 0 && l < L) t[j] = f2bf(xb[l]);
                }
                v = *(const uint4*)t;
            }
            int ba = (ri2 * RS + co * 16) ^ ((ri2 & SWM) << 4);
            *(uint4*)(slab + ba) = v;
        }
    }
    __syncthreads();

    // ---- main loop: ds_read A fragments + MFMA ----
    f32x4 acc[2][4];
#pragma unroll
    for (int mt = 0; mt < 2; ++mt)
#pragma unroll
        for (int g = 0; g < 4; ++g) acc[mt][g] = (f32x4)(0.f);

    const int laneoff0 = q * 16;

    auto compute = [&](int step, bf16x8* bv) {
        int kb, csh, cbyte;
        if (step < S0) { kb = step * 32;        csh = c0shift; cbyte = 0; }
        else           { kb = (step - S0) * 32; csh = cFshift; cbyte = c0bytes; }
        const int tap = kb >> csh;
        const int choff = cbyte + ((kb & ((1 << csh) - 1)) << 1) + laneoff0;
        bf16x8 af[2];
#pragma unroll
        for (int mt = 0; mt < 2; ++mt) {
            int ri = (wm * 2 + mt) * 16 + r + tap;
            int ba = (ri * RS + choff) ^ ((ri & SWM) << 4);
            af[mt] = *(const bf16x8*)(slab + ba);
        }
#pragma unroll
        for (int mt = 0; mt < 2; ++mt)
#pragma unroll
            for (int g = 0; g < 4; ++g)
                acc[mt][g] = __builtin_amdgcn_mfma_f32_16x16x32_bf16(
                    af[mt], bv[g], acc[mt][g], 0, 0, 0);
    };

    int step = 0;
    for (; step + 2 <= S; step += 2) {
        loadB(step + 1, bB);
        compute(step, bA);
        if (step + 2 < S) loadB(step + 2, bA);
        compute(step + 1, bB);
    }
    if (step < S) compute(step, bA);   // odd-S tail (L1: S=7)

    // ---- epilogue: bias, gates, register c-state update, optional BN ----
    const int f = f0 + wn * 16 + r;
    const float b_i = bias[f], b_f = bias[F + f];
    const float b_c = bias[2 * F + f], b_o = bias[3 * F + f];
    float sc = 0.f, sh = 0.f;
    if (bn_out) {
        sc = bn_g[f] * rsqrtf(bn_v[f] + BN_EPS);
        sh = bn_b[f] - bn_m[f] * sc;
    }
#pragma unroll
    for (int mt = 0; mt < 2; ++mt) {
#pragma unroll
        for (int reg = 0; reg < 4; ++reg) {
            const int l = l0 + (wm * 2 + mt) * 16 + q * 4 + reg;
            const long idx = ((long)b * L + l) * F + f;
            float gi = acc[mt][0][reg] + b_i;
            float gf = acc[mt][1][reg] + b_f;
            float gc = acc[mt][2][reg] + b_c;
            float go = acc[mt][3][reg] + b_o;
            float cold = cst[mt][reg];
            float cn = hsig(gf) * cold + hsig(gi) * fmaxf(gc, 0.f);
            float hn = hsig(go) * fmaxf(cn, 0.f);
            cst[mt][reg] = cn;
            h_new[idx] = f2bf(hn);
            if (bn_out) {
                float bv = hn * sc + sh;
                if (bnf32)
                    ((float*)bn_out)[(long)b * bn_bs + (long)l * F + f] = bv;
                else
                    ((ushort*)bn_out)[(long)b * bn_bs + (long)l * F + f] = f2bf(bv);
            }
        }
    }
}

// ---------------------------------------------------------------------------
// The whole network in ONE persistent kernel (512 blocks, 2/CU; LDS 52KB).
// ---------------------------------------------------------------------------
struct FusedArgs {
    const float *x, *Wx1, *Wh1, *b1, *Wx2, *Wh2, *b2, *Wx3, *Wh3, *b3;
    const float *g1, *be1, *m1, *v1, *g2, *be2, *m2, *v2, *g3, *be3, *m3, *v3;
    const float *D1, *db1, *D2, *db2, *D3, *db3;
    ushort *h1seq, *h2seq, *h1a, *h1b, *h2a, *h2b, *h3a, *h3b;
    float *h3bn, *a1, *a2, *partials, *out;
    uint4 *wp1, *wp2, *wp3;
    const ushort *zbuf;
    uint *ctr;
};

__global__ __launch_bounds__(256, 2)
void fused(FusedArgs A)
{
    __shared__ __align__(16) char slab[53248];   // 13*256 slots * 16B (L3 max)
    const int bid = blockIdx.x;
    const int tid = threadIdx.x;
    const int T = 32, L = 128;
    const int F1 = 64, F2 = 128, F3 = 256;

    uint* fullc   = A.ctr;
    uint* invdone = A.ctr + 32;
    uint* tick    = A.ctr + 64;          // tick[x] at ctr[64 + x*32]
    uint epF = 0, epI = 0;
    uint elected = 0, nxcd = 8;

    // ---- per-XCD election via physical XCC_ID + atomic ticket ----
    if (tid == 0) {
        uint xcc;
        asm("s_getreg_b32 %0, hwreg(HW_REG_XCC_ID)" : "=s"(xcc));
        xcc &= 7u;
        uint t = __hip_atomic_fetch_add(&tick[xcc * 32], 1u,
                                        __ATOMIC_RELAXED, __HIP_MEMORY_SCOPE_AGENT);
        elected = (t == 0);
    }

    // ================= phase 0: pack weights + zero h-states ===============
    if (bid < 14)       pack_dev(slab, A.Wx1, 1,  A.Wh1, F1, A.wp1, 1, 7,
                                 bid / 7, bid % 7);
    else if (bid < 86)  pack_dev(slab, A.Wx2, F1, A.Wh2, F2, A.wp2, 6, 18,
                                 (bid - 14) / 18, (bid - 14) % 18);
    else if (bid < 374) pack_dev(slab, A.Wx3, F2, A.Wh3, F3, A.wp3, 12, 36,
                                 (bid - 86) / 36, (bid - 86) % 36);
    {
        const uint4 zero = {0u, 0u, 0u, 0u};
        uint4* z1 = (uint4*)A.h1a;   // 32768 uint4
        uint4* z2 = (uint4*)A.h2a;   // 65536
        uint4* z3 = (uint4*)A.h3a;   // 131072
        for (int g = bid * 256 + tid; g < 229376; g += NB * 256) {
            if (g < 32768) z1[g] = zero;
            else if (g < 98304) z2[g - 32768] = zero;
            else z3[g - 98304] = zero;
        }
    }
    // pre-barrier: after it, tick[] is final -> everyone computes nxcd
    ++epF; gbar(fullc, invdone, epF, 0, elected, nxcd, 0);
    if (tid == 0) {
        nxcd = 0;
        for (int i = 0; i < 8; ++i)
            nxcd += (__hip_atomic_load(&tick[i * 32], __ATOMIC_RELAXED,
                                       __HIP_MEMORY_SCOPE_AGENT) > 0);
        if (nxcd == 0) nxcd = 1;
    }
    // publish pack outputs + zeros (wbl2; no inv needed: first-touch readers)
    ++epF; ++epI; gbar(fullc, invdone, epF, epI, elected, nxcd, 1);

    // ================= diagonal ConvLSTM schedule ==========================
    f32x4 c3[2] = {(f32x4)(0.f), (f32x4)(0.f)};
    f32x4 c2[2] = {(f32x4)(0.f), (f32x4)(0.f)};
    f32x4 c1[2] = {(f32x4)(0.f), (f32x4)(0.f)};

    for (int d = 0; d < T + 2; ++d) {
        int t3 = d - 2;
        if ((unsigned)t3 < (unsigned)T) {
            const ushort* h3o = (t3 & 1) ? A.h3b : A.h3a;
            ushort*       h3n = (t3 & 1) ? A.h3a : A.h3b;
            do_tile<128, 12, 36, 256, 3, 0, 7>(slab, A.zbuf, bid, L,
                    A.h2seq + (long)t3 * L * F2, (long)T * L * F2,
                    h3o, h3n, A.wp3, A.b3,
                    (t3 == T - 1) ? (void*)A.h3bn : nullptr, (long)L * F3, 1,
                    A.g3, A.be3, A.m3, A.v3, c3);
        }
        if (bid < 256) {
            int t2 = d - 1;
            if ((unsigned)t2 < (unsigned)T) {
                const ushort* h2o = (t2 & 1) ? A.h2b : A.h2a;
                ushort*       h2n = (t2 & 1) ? A.h2a : A.h2b;
                do_tile<64, 6, 18, 128, 2, 0, 7>(slab, A.zbuf, bid, L,
                        A.h1seq + (long)t2 * L * F1, (long)T * L * F1,
                        h2o, h2n, A.wp2, A.b2,
                        A.h2seq + (long)t2 * L * F2, (long)T * L * F2, 0,
                        A.g2, A.be2, A.m2, A.v2, c2);
            }
        } else if (bid < 384) {
            int t1 = d;
            if ((unsigned)t1 < (unsigned)T) {
                const ushort* h1o = (t1 & 1) ? A.h1b : A.h1a;
                ushort*       h1n = (t1 & 1) ? A.h1a : A.h1b;
                do_tile<32, 1, 7, 64, 1, 1, 3>(slab, A.zbuf, bid - 256, L,
                        A.x + (long)t1 * L, (long)T * L,
                        h1o, h1n, A.wp1, A.b1,
                        A.h1seq + (long)t1 * L * F1, (long)T * L * F1, 0,
                        A.g1, A.be1, A.m1, A.v1, c1);
            }
        }
        // wbl2 + inv (elected, per XCD): h ping-pong / seq handoff
        ++epF; ++epI; gbar(fullc, invdone, epF, epI, elected, nxcd, 2);
    }

    // ================= dense head ==========================================
    // D1 partial: KT=256, N-tile 256; 512 jobs == 512 blocks.
    {
        __syncthreads();
        float* A_s = (float*)slab;                 // [256][33] = 33.8 KB
        const int n0 = (bid & 3) * 256;
        const int kt = bid >> 2;                   // 0..127
        const int k0 = kt * 256;
        for (int idx = tid; idx < 256 * 32; idx += 256) {
            int m = idx >> 8, k = idx & 255;
            A_s[k * 33 + m] = A.h3bn[(long)m * 32768 + k0 + k];
        }
        __syncthreads();

        const int nq = (tid & 63) * 4;
        const int mg = tid >> 6;
        f32x4 acc[8];
#pragma unroll
        for (int i = 0; i < 8; ++i) acc[i] = (f32x4)(0.f);

        const float* wp0 = &A.D1[(long)k0 * 1024 + n0 + nq];
#define LDW(kk) (*(const f32x4*)(wp0 + (long)(kk) * 1024))
#define DPF(kk, W) do {                                      \
        const float* ap = &A_s[(kk) * 33 + mg * 8];          \
        acc[0] += ap[0] * (W); acc[1] += ap[1] * (W);        \
        acc[2] += ap[2] * (W); acc[3] += ap[3] * (W);        \
        acc[4] += ap[4] * (W); acc[5] += ap[5] * (W);        \
        acc[6] += ap[6] * (W); acc[7] += ap[7] * (W);        \
    } while (0)
        f32x4 wa = LDW(0), wb = LDW(1), wc = LDW(2), wd = LDW(3);
        for (int k = 0; k < 252; k += 4) {
            DPF(k + 0, wa); wa = LDW(k + 4);
            DPF(k + 1, wb); wb = LDW(k + 5);
            DPF(k + 2, wc); wc = LDW(k + 6);
            DPF(k + 3, wd); wd = LDW(k + 7);
        }
        DPF(252, wa); DPF(253, wb); DPF(254, wc); DPF(255, wd);
#undef LDW
#undef DPF
#pragma unroll
        for (int mm = 0; mm < 8; ++mm)
            *(f32x4*)&A.partials[((long)kt * 32 + mg * 8 + mm) * 1024 + n0 + nq] = acc[mm];
    }
    ++epF; ++epI; gbar(fullc, invdone, epF, epI, elected, nxcd, 1);

    // reduce + relu -> a1 [32,1024] (partials first-touch per reader XCD)
    if (bid < 128) {
        int idx = bid * 256 + tid;
        int m = idx >> 10, n = idx & 1023;
        float s = A.db1[n];
#pragma unroll 4
        for (int j = 0; j < 128; ++j)
            s += A.partials[((long)j * 32 + m) * 1024 + n];
        A.a1[idx] = fmaxf(s, 0.f);
    }
    ++epF; ++epI; gbar(fullc, invdone, epF, epI, elected, nxcd, 1);

    // D2 + relu -> a2 [32,512]
    if (bid < 64) {
        float* A_s = (float*)slab;                 // [1024]
        int m = bid >> 1;
        int n = ((bid & 1) << 8) + tid;
        for (int k = tid; k < 1024; k += 256) A_s[k] = A.a1[(long)m * 1024 + k];
        __syncthreads();
        float acc = 0.f;
#pragma unroll 8
        for (int k = 0; k < 1024; ++k)
            acc += A_s[k] * A.D2[(long)k * 512 + n];
        A.a2[(long)m * 512 + n] = fmaxf(acc + A.db2[n], 0.f);
    }
    ++epF; ++epI; gbar(fullc, invdone, epF, epI, elected, nxcd, 1);

    // D3 + softmax -> out [32,5]
    if (bid < 32 && tid < 64) {
        float part[5] = {0.f, 0.f, 0.f, 0.f, 0.f};
        for (int k = tid; k < 512; k += 64) {
            float a = A.a2[bid * 512 + k];
#pragma unroll
            for (int j = 0; j < 5; ++j) part[j] += a * A.D3[k * 5 + j];
        }
        float lg[5];
#pragma unroll
        for (int j = 0; j < 5; ++j) {
            float v = part[j];
            for (int off = 32; off; off >>= 1) v += __shfl_down(v, off);
            lg[j] = v + A.db3[j];
        }
        if (tid == 0) {
            float mx = lg[0];
#pragma unroll
            for (int j = 1; j < 5; ++j) mx = fmaxf(mx, lg[j]);
            float s = 0.f, e[5];
#pragma unroll
            for (int j = 0; j < 5; ++j) { e[j] = expf(lg[j] - mx); s += e[j]; }
#pragma unroll
            for (int j = 0; j < 5; ++j) A.out[bid * 5 + j] = e[j] / s;
        }
    }
}

extern "C" void kernel_launch(void* const* d_in, const int* in_sizes, int n_in,
                              void* d_out, int out_size, void* d_ws, size_t ws_size,
                              hipStream_t stream)
{
    const int B = 32, T = 32, L = 128;
    const int F1 = 64, F2 = 128, F3 = 256;
    (void)in_sizes; (void)n_in; (void)out_size; (void)ws_size;

    // ---- workspace layout ----
    char* p = (char*)d_ws;
    ushort* h1seq = (ushort*)p; p += (size_t)B * T * L * F1 * 2;   // 16.8 MB
    ushort* h2seq = (ushort*)p; p += (size_t)B * T * L * F2 * 2;   // 33.6 MB
    ushort* h1a = (ushort*)p; p += (size_t)B * L * F1 * 2;
    ushort* h1b = (ushort*)p; p += (size_t)B * L * F1 * 2;
    ushort* h2a = (ushort*)p; p += (size_t)B * L * F2 * 2;
    ushort* h2b = (ushort*)p; p += (size_t)B * L * F2 * 2;
    ushort* h3a = (ushort*)p; p += (size_t)B * L * F3 * 2;
    ushort* h3b = (ushort*)p; p += (size_t)B * L * F3 * 2;
    float*  h3bn = (float*)p; p += (size_t)B * L * F3 * 4;
    uint4*  wp1 = (uint4*)p; p += (size_t)2 * 7 * 512 * 16;
    uint4*  wp2 = (uint4*)p; p += (size_t)4 * 18 * 512 * 16;
    uint4*  wp3 = (uint4*)p; p += (size_t)8 * 36 * 512 * 16;
    float*  a1 = (float*)p; p += (size_t)B * 1024 * 4;
    float*  a2 = (float*)p; p += (size_t)B * 512 * 4;
    ushort* zbuf = (ushort*)p; p += 64;
    uint*   ctr = (uint*)p; p += 2048;
    // partials: 128*32*1024*4 = 16.8 MB, aliases dead-by-then h2seq slab
    float* partials = (float*)h2seq;

    FusedArgs A;
    A.x   = (const float*)d_in[0];
    A.Wx1 = (const float*)d_in[1];  A.Wh1 = (const float*)d_in[2];
    A.b1  = (const float*)d_in[3];
    A.Wx2 = (const float*)d_in[4];  A.Wh2 = (const float*)d_in[5];
    A.b2  = (const float*)d_in[6];
    A.Wx3 = (const float*)d_in[7];  A.Wh3 = (const float*)d_in[8];
    A.b3  = (const float*)d_in[9];
    A.g1 = (const float*)d_in[10]; A.be1 = (const float*)d_in[11];
    A.m1 = (const float*)d_in[12]; A.v1  = (const float*)d_in[13];
    A.g2 = (const float*)d_in[14]; A.be2 = (const float*)d_in[15];
    A.m2 = (const float*)d_in[16]; A.v2  = (const float*)d_in[17];
    A.g3 = (const float*)d_in[18]; A.be3 = (const float*)d_in[19];
    A.m3 = (const float*)d_in[20]; A.v3  = (const float*)d_in[21];
    A.D1 = (const float*)d_in[22]; A.db1 = (const float*)d_in[23];
    A.D2 = (const float*)d_in[24]; A.db2 = (const float*)d_in[25];
    A.D3 = (const float*)d_in[26]; A.db3 = (const float*)d_in[27];
    A.h1seq = h1seq; A.h2seq = h2seq;
    A.h1a = h1a; A.h1b = h1b; A.h2a = h2a; A.h2b = h2b;
    A.h3a = h3a; A.h3b = h3b;
    A.h3bn = h3bn; A.a1 = a1; A.a2 = a2; A.partials = partials;
    A.out = (float*)d_out;
    A.wp1 = wp1; A.wp2 = wp2; A.wp3 = wp3;
    A.zbuf = zbuf; A.ctr = ctr;

    hipMemsetAsync(zbuf, 0, 64, stream);
    hipMemsetAsync(ctr, 0, 2048, stream);
    fused<<<NB, 256, 0, stream>>>(A);
}

// Round 8
// 5392.831 us; speedup vs baseline: 1.0031x; 1.0031x over previous
//
#include <hip/hip_runtime.h>
#include <math.h>

#define BN_EPS 1e-3f

typedef unsigned short ushort;
typedef unsigned int uint;
typedef __attribute__((ext_vector_type(8))) short bf16x8;
typedef __attribute__((ext_vector_type(4))) float f32x4;

__device__ __forceinline__ float hsig(float x) {
    return fminf(fmaxf(0.2f * x + 0.5f, 0.f), 1.f);
}
__device__ __forceinline__ ushort f2bf(float f) {
    uint u = __float_as_uint(f);
    u += 0x7fffu + ((u >> 16) & 1u);   // RNE
    return (ushort)(u >> 16);
}

// async global->LDS DMA, 16B/lane; LDS dest = wave-uniform base + lane*16;
// global src per-lane. aux=17 (sc0|sc1): system-scope read -> bypasses /
// never allocates L2, so rewritten cross-XCD data is always read fresh from
// IF. No VGPR destination -> no inline-asm waitcnt hazard (R6's bug).
__device__ __forceinline__ void gld_lds16(const void* g, void* l) {
    __builtin_amdgcn_global_load_lds(
        (const __attribute__((address_space(1))) void*)g,
        (__attribute__((address_space(3))) void*)l, 16, 0, 17);
}

#define NB 512   // 2 blocks/CU on 256 CUs -> guaranteed co-resident

__device__ __forceinline__ void spin_until(uint* p, uint target) {
    int g = 0;
    while (__hip_atomic_load(p, __ATOMIC_RELAXED, __HIP_MEMORY_SCOPE_AGENT) < target) {
        __builtin_amdgcn_s_sleep(2);
        if (++g > (1 << 22)) break;   // degrade to wrong-answer, not hang
    }
}

// Device barrier, NO INVALIDATION EVER (R4/R5/R7 lesson: whole-L2 inv forces
// the per-XCD working set back through IF every interval -> 4-5 ms).
//  flavor 0: arrive+spin only.
//  flavor 1: elected block per XCD does release (buffer_wbl2 = flush dirty
//            set to IF, clean lines stay VALID) and signals; all blocks wait
//            until all nxcd XCDs flushed.
// Freshness for rewritten data comes from sc1-bypass DMA reads, not inv.
__device__ __forceinline__ void gbar(uint* full, uint* invdone,
                                     uint epF, uint epI,
                                     uint elected, uint nxcd, int flavor)
{
    __syncthreads();                       // all stores retired to L2
    if (threadIdx.x == 0) {
        __hip_atomic_fetch_add(full, 1u, __ATOMIC_RELAXED, __HIP_MEMORY_SCOPE_AGENT);
        spin_until(full, epF * NB);        // all blocks' stores are in their L2s
        if (flavor) {
            if (elected) {
                // wbl2: flush this XCD's dirty set to IF
                __hip_atomic_fetch_add(full, 0u, __ATOMIC_RELEASE, __HIP_MEMORY_SCOPE_AGENT);
                asm volatile("s_waitcnt vmcnt(0) lgkmcnt(0)" ::: "memory");
                __hip_atomic_fetch_add(invdone, 1u, __ATOMIC_RELAXED, __HIP_MEMORY_SCOPE_AGENT);
            }
            spin_until(invdone, epI * nxcd);
        }
    }
    asm volatile("" ::: "memory");
    __syncthreads();
}

// ---------------------------------------------------------------------------
// pack (device fn): fp32 weights [3,Cin,4F]+[3,F,4F] -> bf16 fragment order.
// wp is write-once; published by the flavor-1 barrier after phase 0; all
// later reads are cached (weights stay L2-hot -- never invalidated).
// ---------------------------------------------------------------------------
__device__ void pack_dev(char* slab_, const float* __restrict__ Wx, int Cin,
                         const float* __restrict__ Wh, int F,
                         uint4* __restrict__ wp, int S0, int S,
                         int nblk, int step)
{
    ushort (*Wt)[136] = (ushort (*)[136])slab_;
    const int tid = threadIdx.x;
    const int N4 = 4 * F;

    for (int idx = tid; idx < 32 * 128; idx += 256) {
        int kk = idx >> 7, c = idx & 127;
        int gate = c >> 5, fl = c & 31;
        int n = gate * F + nblk * 32 + fl;
        float v = 0.f;
        if (step < S0) {
            int ka = step * 32 + kk;
            if (ka < 3 * Cin) v = Wx[(long)ka * N4 + n];
        } else {
            int ka = (step - S0) * 32 + kk;
            v = Wh[(long)ka * N4 + n];
        }
        Wt[kk][c] = f2bf(v);
    }
    __syncthreads();

    for (int s = tid; s < 512; s += 256) {
        int colgrp = s >> 6, qq = (s >> 4) & 3, rr = s & 15;
        int gate = colgrp >> 1, wn = colgrp & 1;
        int c = gate * 32 + wn * 16 + rr;
        ushort tmp[8];
#pragma unroll
        for (int j = 0; j < 8; ++j) tmp[j] = Wt[qq * 8 + j][c];
        wp[(long)(nblk * S + step) * 512 + s] = *(const uint4*)tmp;
    }
}

// ---------------------------------------------------------------------------
// One gate tile. A slab staged ONCE per interval via sc1-bypass DMA
// (pre-swizzled per-lane sources, lane-linear LDS dest -- rule #21).
// Halo/OOB/im2col lanes redirect their SOURCE to a 64B zero buffer.
// B weights: plain cached loads (write-once, L2-hot), 2-deep rotation.
// SWM: swizzle mask (L1 uses 3: RS=192 only 64-aligned).
// c-state lives in VGPRs across the whole sequence.
// ---------------------------------------------------------------------------
template<int C0A, int S0, int S, int F, int NFLOG, int CIN1, int SWM>
__device__ void do_tile(char* slab, const ushort* __restrict__ zbuf,
        int tile, int L, const void* a0, long a0_bs,
        const ushort* __restrict__ h_old, ushort* __restrict__ h_new,
        const uint4* __restrict__ wp, const float* __restrict__ bias,
        void* bn_out, long bn_bs, int bnf32,
        const float* bn_g, const float* bn_b, const float* bn_m, const float* bn_v,
        f32x4* cst)
{
    __syncthreads();   // prior users of slab (this block) are done

    const int tid = threadIdx.x;
    const int lane = tid & 63;
    const int wave = tid >> 6;
    const int wn = wave & 1, wm = wave >> 1;
    const int q = lane >> 4, r = lane & 15;
    const int fblk = tile & ((1 << NFLOG) - 1);
    const int rest = tile >> NFLOG;
    const int lblk = rest & 1;
    const int b = rest >> 1;
    const int f0 = fblk * 32;
    const int l0 = lblk * 64;
    constexpr int c0shift = 31 - __builtin_clz(C0A);
    constexpr int cFshift = 31 - __builtin_clz(F);
    constexpr int RS = (C0A + F) * 2;       // bytes per slab row
    constexpr int NCH = RS >> 4;            // 16B chunks per row
    constexpr int TOT = 66 * NCH;
    constexpr int NIT = (TOT + 255) >> 8;
    constexpr int c0bytes = C0A * 2;

    // ---- B: direct global->reg fragment loads (cached), double-buffered ----
    const uint4* wpB = wp + (long)fblk * S * 512 + wn * 64 + lane;
    bf16x8 bA[4], bB[4];
    auto loadB = [&](int step, bf16x8* bv) {
#pragma unroll
        for (int g = 0; g < 4; ++g)
            bv[g] = *(const bf16x8*)(wpB + (long)step * 512 + g * 128);
    };
    loadB(0, bA);   // in flight under slab staging

    // ---- stage A slab via bypass-DMA (pre-swizzled sources) ----
    {
        const ushort* a0b = (const ushort*)a0 + (long)b * a0_bs;
        const ushort* hb  = h_old + (long)b * L * F;
        const int wbase = tid & ~63;
#pragma unroll
        for (int it = 0; it < NIT; ++it) {
            const int slot = it * 256 + tid;
            const int ri = slot / NCH;
            const int bo_lin = (slot - ri * NCH) * 16;
            const int boff = bo_lin ^ ((ri & SWM) << 4);   // element coords
            const int l = l0 - 1 + ri;
            const void* src;
            if (ri >= 66 || (unsigned)l >= (unsigned)L ||
                (CIN1 && boff < c0bytes))
                src = (const void*)zbuf;
            else if (boff >= c0bytes)
                src = (const void*)(hb + (long)l * F + ((boff - c0bytes) >> 1));
            else
                src = (const void*)(a0b + (long)l * C0A + (boff >> 1));
            gld_lds16(src, slab + (it * 256 + wbase) * 16);
        }
        asm volatile("s_waitcnt vmcnt(0)" ::: "memory");
    }
    // im2col x-region (L1): overwrite the DMA'd zeros with real taps
    if (CIN1) {
        const float* xb = (const float*)a0 + (long)b * a0_bs;
        for (int s = tid; s < 66 * 4; s += 256) {
            int ri2 = s >> 2, co = s & 3;
            uint4 v = {0u, 0u, 0u, 0u};
            if (co == 0) {
                ushort t[8] = {0, 0, 0, 0, 0, 0, 0, 0};
#pragma unroll
                for (int j = 0; j < 3; ++j) {
                    int l = l0 - 1 + ri2 + j;
                    if (l >= 0 && l < L) t[j] = f2bf(xb[l]);
                }
                v = *(const uint4*)t;
            }
            int ba = (ri2 * RS + co * 16) ^ ((ri2 & SWM) << 4);
            *(uint4*)(slab + ba) = v;
        }
    }
    __syncthreads();

    // ---- main loop: ds_read A fragments + MFMA ----
    f32x4 acc[2][4];
#pragma unroll
    for (int mt = 0; mt < 2; ++mt)
#pragma unroll
        for (int g = 0; g < 4; ++g) acc[mt][g] = (f32x4)(0.f);

    const int laneoff0 = q * 16;

    auto compute = [&](int step, bf16x8* bv) {
        int kb, csh, cbyte;
        if (step < S0) { kb = step * 32;        csh = c0shift; cbyte = 0; }
        else           { kb = (step - S0) * 32; csh = cFshift; cbyte = c0bytes; }
        const int tap = kb >> csh;
        const int choff = cbyte + ((kb & ((1 << csh) - 1)) << 1) + laneoff0;
        bf16x8 af[2];
#pragma unroll
        for (int mt = 0; mt < 2; ++mt) {
            int ri = (wm * 2 + mt) * 16 + r + tap;
            int ba = (ri * RS + choff) ^ ((ri & SWM) << 4);
            af[mt] = *(const bf16x8*)(slab + ba);
        }
#pragma unroll
        for (int mt = 0; mt < 2; ++mt)
#pragma unroll
            for (int g = 0; g < 4; ++g)
                acc[mt][g] = __builtin_amdgcn_mfma_f32_16x16x32_bf16(
                    af[mt], bv[g], acc[mt][g], 0, 0, 0);
    };

    int step = 0;
    for (; step + 2 <= S; step += 2) {
        loadB(step + 1, bB);
        compute(step, bA);
        if (step + 2 < S) loadB(step + 2, bA);
        compute(step + 1, bB);
    }
    if (step < S) compute(step, bA);   // odd-S tail (L1: S=7)

    // ---- epilogue: bias, gates, register c-state update, optional BN ----
    const int f = f0 + wn * 16 + r;
    const float b_i = bias[f], b_f = bias[F + f];
    const float b_c = bias[2 * F + f], b_o = bias[3 * F + f];
    float sc = 0.f, sh = 0.f;
    if (bn_out) {
        sc = bn_g[f] * rsqrtf(bn_v[f] + BN_EPS);
        sh = bn_b[f] - bn_m[f] * sc;
    }
#pragma unroll
    for (int mt = 0; mt < 2; ++mt) {
#pragma unroll
        for (int reg = 0; reg < 4; ++reg) {
            const int l = l0 + (wm * 2 + mt) * 16 + q * 4 + reg;
            const long idx = ((long)b * L + l) * F + f;
            float gi = acc[mt][0][reg] + b_i;
            float gf = acc[mt][1][reg] + b_f;
            float gc = acc[mt][2][reg] + b_c;
            float go = acc[mt][3][reg] + b_o;
            float cold = cst[mt][reg];
            float cn = hsig(gf) * cold + hsig(gi) * fmaxf(gc, 0.f);
            float hn = hsig(go) * fmaxf(cn, 0.f);
            cst[mt][reg] = cn;
            h_new[idx] = f2bf(hn);
            if (bn_out) {
                float bv = hn * sc + sh;
                if (bnf32)
                    ((float*)bn_out)[(long)b * bn_bs + (long)l * F + f] = bv;
                else
                    ((ushort*)bn_out)[(long)b * bn_bs + (long)l * F + f] = f2bf(bv);
            }
        }
    }
}

// ---------------------------------------------------------------------------
// The whole network in ONE persistent kernel (512 blocks, 2/CU; LDS 52KB).
// Coherence scheme: writers store cached; per-XCD elected wbl2 at barriers;
// readers of rewritten data use sc1-bypass DMA; NO L2 invalidation ever.
// ---------------------------------------------------------------------------
struct FusedArgs {
    const float *x, *Wx1, *Wh1, *b1, *Wx2, *Wh2, *b2, *Wx3, *Wh3, *b3;
    const float *g1, *be1, *m1, *v1, *g2, *be2, *m2, *v2, *g3, *be3, *m3, *v3;
    const float *D1, *db1, *D2, *db2, *D3, *db3;
    ushort *h1seq, *h2seq, *h1a, *h1b, *h2a, *h2b, *h3a, *h3b;
    float *h3bn, *a1, *a2, *partials, *out;
    uint4 *wp1, *wp2, *wp3;
    const ushort *zbuf;
    uint *ctr;
};

__global__ __launch_bounds__(256, 2)
void fused(FusedArgs A)
{
    __shared__ __align__(16) char slab[53248];   // 13*256 slots * 16B (L3 max)
    const int bid = blockIdx.x;
    const int tid = threadIdx.x;
    const int T = 32, L = 128;
    const int F1 = 64, F2 = 128, F3 = 256;

    uint* fullc   = A.ctr;
    uint* invdone = A.ctr + 32;
    uint* tick    = A.ctr + 64;          // tick[x] at ctr[64 + x*32]
    uint epF = 0, epI = 0;
    uint elected = 0, nxcd = 8;

    // ---- per-XCD election via physical XCC_ID + atomic ticket ----
    if (tid == 0) {
        uint xcc;
        asm("s_getreg_b32 %0, hwreg(HW_REG_XCC_ID)" : "=s"(xcc));
        xcc &= 7u;
        uint t = __hip_atomic_fetch_add(&tick[xcc * 32], 1u,
                                        __ATOMIC_RELAXED, __HIP_MEMORY_SCOPE_AGENT);
        elected = (t == 0);
    }

    // ================= phase 0: pack weights + zero h-states ===============
    if (bid < 14)       pack_dev(slab, A.Wx1, 1,  A.Wh1, F1, A.wp1, 1, 7,
                                 bid / 7, bid % 7);
    else if (bid < 86)  pack_dev(slab, A.Wx2, F1, A.Wh2, F2, A.wp2, 6, 18,
                                 (bid - 14) / 18, (bid - 14) % 18);
    else if (bid < 374) pack_dev(slab, A.Wx3, F2, A.Wh3, F3, A.wp3, 12, 36,
                                 (bid - 86) / 36, (bid - 86) % 36);
    {
        const uint4 zero = {0u, 0u, 0u, 0u};
        uint4* z1 = (uint4*)A.h1a;   // 32768 uint4
        uint4* z2 = (uint4*)A.h2a;   // 65536
        uint4* z3 = (uint4*)A.h3a;   // 131072
        for (int g = bid * 256 + tid; g < 229376; g += NB * 256) {
            if (g < 32768) z1[g] = zero;
            else if (g < 98304) z2[g - 32768] = zero;
            else z3[g - 98304] = zero;
        }
    }
    // pre-barrier: after it, tick[] is final -> everyone computes nxcd
    ++epF; gbar(fullc, invdone, epF, 0, elected, nxcd, 0);
    if (tid == 0) {
        nxcd = 0;
        for (int i = 0; i < 8; ++i)
            nxcd += (__hip_atomic_load(&tick[i * 32], __ATOMIC_RELAXED,
                                       __HIP_MEMORY_SCOPE_AGENT) > 0);
        if (nxcd == 0) nxcd = 1;
    }
    // publish pack outputs + zeros (elected wbl2 per XCD)
    ++epF; ++epI; gbar(fullc, invdone, epF, epI, elected, nxcd, 1);

    // ================= diagonal ConvLSTM schedule ==========================
    f32x4 c3[2] = {(f32x4)(0.f), (f32x4)(0.f)};
    f32x4 c2[2] = {(f32x4)(0.f), (f32x4)(0.f)};
    f32x4 c1[2] = {(f32x4)(0.f), (f32x4)(0.f)};

    for (int d = 0; d < T + 2; ++d) {
        int t3 = d - 2;
        if ((unsigned)t3 < (unsigned)T) {
            const ushort* h3o = (t3 & 1) ? A.h3b : A.h3a;
            ushort*       h3n = (t3 & 1) ? A.h3a : A.h3b;
            do_tile<128, 12, 36, 256, 3, 0, 7>(slab, A.zbuf, bid, L,
                    A.h2seq + (long)t3 * L * F2, (long)T * L * F2,
                    h3o, h3n, A.wp3, A.b3,
                    (t3 == T - 1) ? (void*)A.h3bn : nullptr, (long)L * F3, 1,
                    A.g3, A.be3, A.m3, A.v3, c3);
        }
        if (bid < 256) {
            int t2 = d - 1;
            if ((unsigned)t2 < (unsigned)T) {
                const ushort* h2o = (t2 & 1) ? A.h2b : A.h2a;
                ushort*       h2n = (t2 & 1) ? A.h2a : A.h2b;
                do_tile<64, 6, 18, 128, 2, 0, 7>(slab, A.zbuf, bid, L,
                        A.h1seq + (long)t2 * L * F1, (long)T * L * F1,
                        h2o, h2n, A.wp2, A.b2,
                        A.h2seq + (long)t2 * L * F2, (long)T * L * F2, 0,
                        A.g2, A.be2, A.m2, A.v2, c2);
            }
        } else if (bid < 384) {
            int t1 = d;
            if ((unsigned)t1 < (unsigned)T) {
                const ushort* h1o = (t1 & 1) ? A.h1b : A.h1a;
                ushort*       h1n = (t1 & 1) ? A.h1a : A.h1b;
                do_tile<32, 1, 7, 64, 1, 1, 3>(slab, A.zbuf, bid - 256, L,
                        A.x + (long)t1 * L, (long)T * L,
                        h1o, h1n, A.wp1, A.b1,
                        A.h1seq + (long)t1 * L * F1, (long)T * L * F1, 0,
                        A.g1, A.be1, A.m1, A.v1, c1);
            }
        }
        // elected wbl2 per XCD: publish h ping-pong / seq handoff to IF
        ++epF; ++epI; gbar(fullc, invdone, epF, epI, elected, nxcd, 1);
    }

    // ================= dense head ==========================================
    // D1 partial: KT=256, N-tile 256; 512 jobs == 512 blocks.
    // h3bn / D1 write-once or read-only + first-touch readers -> cached.
    {
        __syncthreads();
        float* A_s = (float*)slab;                 // [256][33] = 33.8 KB
        const int n0 = (bid & 3) * 256;
        const int kt = bid >> 2;                   // 0..127
        const int k0 = kt * 256;
        for (int idx = tid; idx < 256 * 32; idx += 256) {
            int m = idx >> 8, k = idx & 255;
            A_s[k * 33 + m] = A.h3bn[(long)m * 32768 + k0 + k];
        }
        __syncthreads();

        const int nq = (tid & 63) * 4;
        const int mg = tid >> 6;
        f32x4 acc[8];
#pragma unroll
        for (int i = 0; i < 8; ++i) acc[i] = (f32x4)(0.f);

        const float* wp0 = &A.D1[(long)k0 * 1024 + n0 + nq];
#define LDW(kk) (*(const f32x4*)(wp0 + (long)(kk) * 1024))
#define DPF(kk, W) do {                                      \
        const float* ap = &A_s[(kk) * 33 + mg * 8];          \
        acc[0] += ap[0] * (W); acc[1] += ap[1] * (W);        \
        acc[2] += ap[2] * (W); acc[3] += ap[3] * (W);        \
        acc[4] += ap[4] * (W); acc[5] += ap[5] * (W);        \
        acc[6] += ap[6] * (W); acc[7] += ap[7] * (W);        \
    } while (0)
        f32x4 wa = LDW(0), wb = LDW(1), wc = LDW(2), wd = LDW(3);
        for (int k = 0; k < 252; k += 4) {
            DPF(k + 0, wa); wa = LDW(k + 4);
            DPF(k + 1, wb); wb = LDW(k + 5);
            DPF(k + 2, wc); wc = LDW(k + 6);
            DPF(k + 3, wd); wd = LDW(k + 7);
        }
        DPF(252, wa); DPF(253, wb); DPF(254, wc); DPF(255, wd);
#undef LDW
#undef DPF
#pragma unroll
        for (int mm = 0; mm < 8; ++mm)
            *(f32x4*)&A.partials[((long)kt * 32 + mg * 8 + mm) * 1024 + n0 + nq] = acc[mm];
    }
    ++epF; ++epI; gbar(fullc, invdone, epF, epI, elected, nxcd, 1);

    // reduce + relu -> a1 [32,1024]. partials is a FRESH region (no aliasing,
    // R6 bug fix): writers first-touch, flushed; readers first-touch -> cached
    // loads are coherent.
    if (bid < 128) {
        int idx = bid * 256 + tid;
        int m = idx >> 10, n = idx & 1023;
        float s = A.db1[n];
#pragma unroll 4
        for (int j = 0; j < 128; ++j)
            s += A.partials[((long)j * 32 + m) * 1024 + n];
        A.a1[idx] = fmaxf(s, 0.f);
    }
    ++epF; ++epI; gbar(fullc, invdone, epF, epI, elected, nxcd, 1);

    // D2 + relu -> a2 [32,512]
    if (bid < 64) {
        float* A_s = (float*)slab;                 // [1024]
        int m = bid >> 1;
        int n = ((bid & 1) << 8) + tid;
        for (int k = tid; k < 1024; k += 256) A_s[k] = A.a1[(long)m * 1024 + k];
        __syncthreads();
        float acc = 0.f;
#pragma unroll 8
        for (int k = 0; k < 1024; ++k)
            acc += A_s[k] * A.D2[(long)k * 512 + n];
        A.a2[(long)m * 512 + n] = fmaxf(acc + A.db2[n], 0.f);
    }
    ++epF; ++epI; gbar(fullc, invdone, epF, epI, elected, nxcd, 1);

    // D3 + softmax -> out [32,5]
    if (bid < 32 && tid < 64) {
        float part[5] = {0.f, 0.f, 0.f, 0.f, 0.f};
        for (int k = tid; k < 512; k += 64) {
            float a = A.a2[bid * 512 + k];
#pragma unroll
            for (int j = 0; j < 5; ++j) part[j] += a * A.D3[k * 5 + j];
        }
        float lg[5];
#pragma unroll
        for (int j = 0; j < 5; ++j) {
            float v = part[j];
            for (int off = 32; off; off >>= 1) v += __shfl_down(v, off);
            lg[j] = v + A.db3[j];
        }
        if (tid == 0) {
            float mx = lg[0];
#pragma unroll
            for (int j = 1; j < 5; ++j) mx = fmaxf(mx, lg[j]);
            float s = 0.f, e[5];
#pragma unroll
            for (int j = 0; j < 5; ++j) { e[j] = expf(lg[j] - mx); s += e[j]; }
#pragma unroll
            for (int j = 0; j < 5; ++j) A.out[bid * 5 + j] = e[j] / s;
        }
    }
}

extern "C" void kernel_launch(void* const* d_in, const int* in_sizes, int n_in,
                              void* d_out, int out_size, void* d_ws, size_t ws_size,
                              hipStream_t stream)
{
    const int B = 32, T = 32, L = 128;
    const int F1 = 64, F2 = 128, F3 = 256;
    (void)in_sizes; (void)n_in; (void)out_size; (void)ws_size;

    // ---- workspace layout (~92 MB; workspace is ~512 MB per re-poison) ----
    char* p = (char*)d_ws;
    ushort* h1seq = (ushort*)p; p += (size_t)B * T * L * F1 * 2;   // 16.8 MB
    ushort* h2seq = (ushort*)p; p += (size_t)B * T * L * F2 * 2;   // 33.6 MB
    ushort* h1a = (ushort*)p; p += (size_t)B * L * F1 * 2;
    ushort* h1b = (ushort*)p; p += (size_t)B * L * F1 * 2;
    ushort* h2a = (ushort*)p; p += (size_t)B * L * F2 * 2;
    ushort* h2b = (ushort*)p; p += (size_t)B * L * F2 * 2;
    ushort* h3a = (ushort*)p; p += (size_t)B * L * F3 * 2;
    ushort* h3b = (ushort*)p; p += (size_t)B * L * F3 * 2;
    float*  h3bn = (float*)p; p += (size_t)B * L * F3 * 4;
    uint4*  wp1 = (uint4*)p; p += (size_t)2 * 7 * 512 * 16;
    uint4*  wp2 = (uint4*)p; p += (size_t)4 * 18 * 512 * 16;
    uint4*  wp3 = (uint4*)p; p += (size_t)8 * 36 * 512 * 16;
    float*  a1 = (float*)p; p += (size_t)B * 1024 * 4;
    float*  a2 = (float*)p; p += (size_t)B * 512 * 4;
    ushort* zbuf = (ushort*)p; p += 128;
    uint*   ctr = (uint*)p; p += 2048;
    float*  partials = (float*)p; p += (size_t)128 * 32 * 1024 * 4;  // 16.8 MB, OWN region

    FusedArgs A;
    A.x   = (const float*)d_in[0];
    A.Wx1 = (const float*)d_in[1];  A.Wh1 = (const float*)d_in[2];
    A.b1  = (const float*)d_in[3];
    A.Wx2 = (const float*)d_in[4];  A.Wh2 = (const float*)d_in[5];
    A.b2  = (const float*)d_in[6];
    A.Wx3 = (const float*)d_in[7];  A.Wh3 = (const float*)d_in[8];
    A.b3  = (const float*)d_in[9];
    A.g1 = (const float*)d_in[10]; A.be1 = (const float*)d_in[11];
    A.m1 = (const float*)d_in[12]; A.v1  = (const float*)d_in[13];
    A.g2 = (const float*)d_in[14]; A.be2 = (const float*)d_in[15];
    A.m2 = (const float*)d_in[16]; A.v2  = (const float*)d_in[17];
    A.g3 = (const float*)d_in[18]; A.be3 = (const float*)d_in[19];
    A.m3 = (const float*)d_in[20]; A.v3  = (const float*)d_in[21];
    A.D1 = (const float*)d_in[22]; A.db1 = (const float*)d_in[23];
    A.D2 = (const float*)d_in[24]; A.db2 = (const float*)d_in[25];
    A.D3 = (const float*)d_in[26]; A.db3 = (const float*)d_in[27];
    A.h1seq = h1seq; A.h2seq = h2seq;
    A.h1a = h1a; A.h1b = h1b; A.h2a = h2a; A.h2b = h2b;
    A.h3a = h3a; A.h3b = h3b;
    A.h3bn = h3bn; A.a1 = a1; A.a2 = a2; A.partials = partials;
    A.out = (float*)d_out;
    A.wp1 = wp1; A.wp2 = wp2; A.wp3 = wp3;
    A.zbuf = zbuf; A.ctr = ctr;

    hipMemsetAsync(zbuf, 0, 128, stream);
    hipMemsetAsync(ctr, 0, 2048, stream);
    fused<<<NB, 256, 0, stream>>>(A);
}

// Round 9
// 1471.753 us; speedup vs baseline: 3.6756x; 3.6642x over previous
//
#include <hip/hip_runtime.h>
#include <math.h>

#define BN_EPS 1e-3f

typedef unsigned short ushort;
typedef unsigned int uint;
typedef __attribute__((ext_vector_type(8))) short bf16x8;
typedef __attribute__((ext_vector_type(4))) float f32x4;

__device__ __forceinline__ float hsig(float x) {
    return fminf(fmaxf(0.2f * x + 0.5f, 0.f), 1.f);
}
__device__ __forceinline__ ushort f2bf(float f) {
    uint u = __float_as_uint(f);
    u += 0x7fffu + ((u >> 16) & 1u);   // RNE
    return (ushort)(u >> 16);
}

// async global->LDS DMA, 16B/lane; LDS dest = wave-uniform base + lane*16;
// global src per-lane. aux=1 (sc0): agent-scope read -> bypasses the CU's
// vector L1 (not coherent across CUs) and is served by the XCD L2, which IS
// the coherence point for our XCD-local producer->consumer scheme.
// R7/R8 used sc0|sc1 (system bypass) -> 4.7 GB uncached refetch; sc0-only
// keeps the stream L2-hot.
__device__ __forceinline__ void gld_lds16(const void* g, void* l) {
    __builtin_amdgcn_global_load_lds(
        (const __attribute__((address_space(1))) void*)g,
        (__attribute__((address_space(3))) void*)l, 16, 0, 1);
}

#define NB 512   // 2 blocks/CU on 256 CUs -> guaranteed co-resident

__device__ __forceinline__ void spin_until(uint* p, uint target) {
    int g = 0;
    while (__hip_atomic_load(p, __ATOMIC_RELAXED, __HIP_MEMORY_SCOPE_AGENT) < target) {
        __builtin_amdgcn_s_sleep(2);
        if (++g > (1 << 22)) break;   // degrade to wrong-answer, not hang
    }
}

// GLOBAL barrier (used only at phase boundaries, ~6 total):
//  flavor 0: arrive+spin.
//  flavor 1: + elected block per XCD does release (buffer_wbl2 = flush dirty
//            set to IF; clean lines stay valid) and signals; all wait for
//            all nxcd XCDs. NO invalidate anywhere (R4/R5/R7 lesson).
__device__ __forceinline__ void gbar(uint* full, uint* invdone,
                                     uint epF, uint epI,
                                     uint elected, uint nxcd, int flavor)
{
    __syncthreads();                       // all stores retired to L2
    if (threadIdx.x == 0) {
        __hip_atomic_fetch_add(full, 1u, __ATOMIC_RELAXED, __HIP_MEMORY_SCOPE_AGENT);
        spin_until(full, epF * NB);
        if (flavor) {
            if (elected) {
                __hip_atomic_fetch_add(full, 0u, __ATOMIC_RELEASE, __HIP_MEMORY_SCOPE_AGENT);
                asm volatile("s_waitcnt vmcnt(0) lgkmcnt(0)" ::: "memory");
                __hip_atomic_fetch_add(invdone, 1u, __ATOMIC_RELAXED, __HIP_MEMORY_SCOPE_AGENT);
            }
            spin_until(invdone, epI * nxcd);
        }
    }
    asm volatile("" ::: "memory");
    __syncthreads();
}

// ---------------------------------------------------------------------------
// pack (device fn): fp32 weights [3,Cin,4F]+[3,F,4F] -> bf16 fragment order.
// wp is write-once; published once by the flavor-1 barrier after phase 0;
// weight lines then stay L1/L2-hot forever (never invalidated).
// ---------------------------------------------------------------------------
__device__ void pack_dev(char* slab_, const float* __restrict__ Wx, int Cin,
                         const float* __restrict__ Wh, int F,
                         uint4* __restrict__ wp, int S0, int S,
                         int nblk, int step)
{
    ushort (*Wt)[136] = (ushort (*)[136])slab_;
    const int tid = threadIdx.x;
    const int N4 = 4 * F;

    for (int idx = tid; idx < 32 * 128; idx += 256) {
        int kk = idx >> 7, c = idx & 127;
        int gate = c >> 5, fl = c & 31;
        int n = gate * F + nblk * 32 + fl;
        float v = 0.f;
        if (step < S0) {
            int ka = step * 32 + kk;
            if (ka < 3 * Cin) v = Wx[(long)ka * N4 + n];
        } else {
            int ka = (step - S0) * 32 + kk;
            v = Wh[(long)ka * N4 + n];
        }
        Wt[kk][c] = f2bf(v);
    }
    __syncthreads();

    for (int s = tid; s < 512; s += 256) {
        int colgrp = s >> 6, qq = (s >> 4) & 3, rr = s & 15;
        int gate = colgrp >> 1, wn = colgrp & 1;
        int c = gate * 32 + wn * 16 + rr;
        ushort tmp[8];
#pragma unroll
        for (int j = 0; j < 8; ++j) tmp[j] = Wt[qq * 8 + j][c];
        wp[(long)(nblk * S + step) * 512 + s] = *(const uint4*)tmp;
    }
}

// ---------------------------------------------------------------------------
// One gate tile. A slab staged once per interval via sc0-DMA (L2-served,
// L1-bypassed -> coherent with same-XCD writers; pre-swizzled per-lane
// sources, lane-linear LDS dest -- rule #21). Halo/OOB lanes read zbuf.
// B weights: plain cached loads (write-once, L1/L2-hot), 2-deep rotation.
// c-state: global fp32, XCD-local (tile's own rows only -> self-coherent).
// SWM: swizzle mask (L1 layer uses 3: RS=192 only 64-aligned).
// ---------------------------------------------------------------------------
template<int C0A, int S0, int S, int F, int NFLOG, int CIN1, int SWM>
__device__ void do_tile(char* slab, const ushort* __restrict__ zbuf,
        int tile, int L, const void* a0, long a0_bs,
        const ushort* __restrict__ h_old, ushort* __restrict__ h_new,
        const uint4* __restrict__ wp, const float* __restrict__ bias,
        float* __restrict__ c_state,
        void* bn_out, long bn_bs, int bnf32,
        const float* bn_g, const float* bn_b, const float* bn_m, const float* bn_v)
{
    __syncthreads();   // prior users of slab (this block) are done

    const int tid = threadIdx.x;
    const int lane = tid & 63;
    const int wave = tid >> 6;
    const int wn = wave & 1, wm = wave >> 1;
    const int q = lane >> 4, r = lane & 15;
    const int fblk = tile & ((1 << NFLOG) - 1);
    const int rest = tile >> NFLOG;
    const int lblk = rest & 1;
    const int b = rest >> 1;
    const int f0 = fblk * 32;
    const int l0 = lblk * 64;
    constexpr int c0shift = 31 - __builtin_clz(C0A);
    constexpr int cFshift = 31 - __builtin_clz(F);
    constexpr int RS = (C0A + F) * 2;       // bytes per slab row
    constexpr int NCH = RS >> 4;            // 16B chunks per row
    constexpr int TOT = 66 * NCH;
    constexpr int NIT = (TOT + 255) >> 8;
    constexpr int c0bytes = C0A * 2;

    // ---- B: direct global->reg fragment loads (cached), double-buffered ----
    const uint4* wpB = wp + (long)fblk * S * 512 + wn * 64 + lane;
    bf16x8 bA[4], bB[4];
    auto loadB = [&](int step, bf16x8* bv) {
#pragma unroll
        for (int g = 0; g < 4; ++g)
            bv[g] = *(const bf16x8*)(wpB + (long)step * 512 + g * 128);
    };
    loadB(0, bA);   // in flight under slab staging

    // ---- stage A slab via sc0-DMA (pre-swizzled sources) ----
    {
        const ushort* a0b = (const ushort*)a0 + (long)b * a0_bs;
        const ushort* hb  = h_old + (long)b * L * F;
        const int wbase = tid & ~63;
#pragma unroll
        for (int it = 0; it < NIT; ++it) {
            const int slot = it * 256 + tid;
            const int ri = slot / NCH;
            const int bo_lin = (slot - ri * NCH) * 16;
            const int boff = bo_lin ^ ((ri & SWM) << 4);   // element coords
            const int l = l0 - 1 + ri;
            const void* src;
            if (ri >= 66 || (unsigned)l >= (unsigned)L ||
                (CIN1 && boff < c0bytes))
                src = (const void*)zbuf;
            else if (boff >= c0bytes)
                src = (const void*)(hb + (long)l * F + ((boff - c0bytes) >> 1));
            else
                src = (const void*)(a0b + (long)l * C0A + (boff >> 1));
            gld_lds16(src, slab + (it * 256 + wbase) * 16);
        }
        asm volatile("s_waitcnt vmcnt(0)" ::: "memory");
    }
    // im2col x-region (L1): overwrite the DMA'd zeros with real taps
    if (CIN1) {
        const float* xb = (const float*)a0 + (long)b * a0_bs;
        for (int s = tid; s < 66 * 4; s += 256) {
            int ri2 = s >> 2, co = s & 3;
            uint4 v = {0u, 0u, 0u, 0u};
            if (co == 0) {
                ushort t[8] = {0, 0, 0, 0, 0, 0, 0, 0};
#pragma unroll
                for (int j = 0; j < 3; ++j) {
                    int l = l0 - 1 + ri2 + j;
                    if (l >= 0 && l < L) t[j] = f2bf(xb[l]);
                }
                v = *(const uint4*)t;
            }
            int ba = (ri2 * RS + co * 16) ^ ((ri2 & SWM) << 4);
            *(uint4*)(slab + ba) = v;
        }
    }
    __syncthreads();

    // ---- main loop: ds_read A fragments + MFMA ----
    f32x4 acc[2][4];
#pragma unroll
    for (int mt = 0; mt < 2; ++mt)
#pragma unroll
        for (int g = 0; g < 4; ++g) acc[mt][g] = (f32x4)(0.f);

    const int laneoff0 = q * 16;

    auto compute = [&](int step, bf16x8* bv) {
        int kb, csh, cbyte;
        if (step < S0) { kb = step * 32;        csh = c0shift; cbyte = 0; }
        else           { kb = (step - S0) * 32; csh = cFshift; cbyte = c0bytes; }
        const int tap = kb >> csh;
        const int choff = cbyte + ((kb & ((1 << csh) - 1)) << 1) + laneoff0;
        bf16x8 af[2];
#pragma unroll
        for (int mt = 0; mt < 2; ++mt) {
            int ri = (wm * 2 + mt) * 16 + r + tap;
            int ba = (ri * RS + choff) ^ ((ri & SWM) << 4);
            af[mt] = *(const bf16x8*)(slab + ba);
        }
#pragma unroll
        for (int mt = 0; mt < 2; ++mt)
#pragma unroll
            for (int g = 0; g < 4; ++g)
                acc[mt][g] = __builtin_amdgcn_mfma_f32_16x16x32_bf16(
                    af[mt], bv[g], acc[mt][g], 0, 0, 0);
    };

    int step = 0;
    for (; step + 2 <= S; step += 2) {
        loadB(step + 1, bB);
        compute(step, bA);
        if (step + 2 < S) loadB(step + 2, bA);
        compute(step + 1, bB);
    }
    if (step < S) compute(step, bA);   // odd-S tail (L1: S=7)

    // ---- epilogue: bias, gates, c-state update (global, XCD-local), BN ----
    const int f = f0 + wn * 16 + r;
    const float b_i = bias[f], b_f = bias[F + f];
    const float b_c = bias[2 * F + f], b_o = bias[3 * F + f];
    float sc = 0.f, sh = 0.f;
    if (bn_out) {
        sc = bn_g[f] * rsqrtf(bn_v[f] + BN_EPS);
        sh = bn_b[f] - bn_m[f] * sc;
    }
#pragma unroll
    for (int mt = 0; mt < 2; ++mt) {
#pragma unroll
        for (int reg = 0; reg < 4; ++reg) {
            const int l = l0 + (wm * 2 + mt) * 16 + q * 4 + reg;
            const long idx = ((long)b * L + l) * F + f;
            float gi = acc[mt][0][reg] + b_i;
            float gf = acc[mt][1][reg] + b_f;
            float gc = acc[mt][2][reg] + b_c;
            float go = acc[mt][3][reg] + b_o;
            float cold = c_state[idx];
            float cn = hsig(gf) * cold + hsig(gi) * fmaxf(gc, 0.f);
            float hn = hsig(go) * fmaxf(cn, 0.f);
            c_state[idx] = cn;
            h_new[idx] = f2bf(hn);
            if (bn_out) {
                float bv = hn * sc + sh;
                if (bnf32)
                    ((float*)bn_out)[(long)b * bn_bs + (long)l * F + f] = bv;
                else
                    ((ushort*)bn_out)[(long)b * bn_bs + (long)l * F + f] = f2bf(bv);
            }
        }
    }
}

// ---------------------------------------------------------------------------
// The whole network in ONE persistent kernel (512 blocks, 2/CU; LDS 52KB).
// XCD-LOCAL ownership: all tiles of batch b live on physical XCD b%8
// (discovered via HW_REG_XCC_ID + ticket). The entire ConvLSTM time loop
// needs only per-XCD barriers and zero cache maintenance: writers store
// cached (dirty in own L2), readers use sc0 (L1-bypass, L2-served).
// Cross-XCD handoffs (pack outputs, h3bn, dense chain) use global flavor-1
// barriers with one elected wbl2 per XCD -- the already-proven R8 machinery.
// ---------------------------------------------------------------------------
struct FusedArgs {
    const float *x, *Wx1, *Wh1, *b1, *Wx2, *Wh2, *b2, *Wx3, *Wh3, *b3;
    const float *g1, *be1, *m1, *v1, *g2, *be2, *m2, *v2, *g3, *be3, *m3, *v3;
    const float *D1, *db1, *D2, *db2, *D3, *db3;
    ushort *h1seq, *h2seq, *h1a, *h1b, *h2a, *h2b, *h3a, *h3b;
    float *c1s, *c2s, *c3s;
    float *h3bn, *a1, *a2, *partials, *out;
    uint4 *wp1, *wp2, *wp3;
    const ushort *zbuf;
    uint *ctr;
};

__global__ __launch_bounds__(256, 2)
void fused(FusedArgs A)
{
    __shared__ __align__(16) char slab[53248];   // 13*256 slots * 16B (L3 max)
    __shared__ int shmeta[3];                    // rank, nbx, xcd
    const int bid = blockIdx.x;
    const int tid = threadIdx.x;
    const int T = 32, L = 128;
    const int F1 = 64, F2 = 128, F3 = 256;

    uint* fullc   = A.ctr;
    uint* invdone = A.ctr + 32;
    uint* tick    = A.ctr + 64;          // tick[x] at ctr[64 + x*32]
    uint* xctr    = A.ctr + 512;         // xctr[x] at ctr[512 + x*32]
    uint elected = 0, nxcd = 8;

    // ---- physical-XCD rank via XCC_ID + atomic ticket ----
    if (tid == 0) {
        uint xcc;
        asm("s_getreg_b32 %0, hwreg(HW_REG_XCC_ID)" : "=s"(xcc));
        xcc &= 7u;
        uint t = __hip_atomic_fetch_add(&tick[xcc * 32], 1u,
                                        __ATOMIC_RELAXED, __HIP_MEMORY_SCOPE_AGENT);
        elected = (t == 0);
        shmeta[0] = (int)t;
        shmeta[2] = (int)xcc;
    }

    // ================= phase 0: pack weights + zero states =================
    if (bid < 14)       pack_dev(slab, A.Wx1, 1,  A.Wh1, F1, A.wp1, 1, 7,
                                 bid / 7, bid % 7);
    else if (bid < 86)  pack_dev(slab, A.Wx2, F1, A.Wh2, F2, A.wp2, 6, 18,
                                 (bid - 14) / 18, (bid - 14) % 18);
    else if (bid < 374) pack_dev(slab, A.Wx3, F2, A.Wh3, F3, A.wp3, 12, 36,
                                 (bid - 86) / 36, (bid - 86) % 36);
    {
        const uint4 zero = {0u, 0u, 0u, 0u};
        uint4* z1 = (uint4*)A.h1a;   //  32768 uint4
        uint4* z2 = (uint4*)A.h2a;   //  65536
        uint4* z3 = (uint4*)A.h3a;   // 131072
        uint4* zc1 = (uint4*)A.c1s;  //  65536
        uint4* zc2 = (uint4*)A.c2s;  // 131072
        uint4* zc3 = (uint4*)A.c3s;  // 262144
        for (int g = bid * 256 + tid; g < 688128; g += NB * 256) {
            if (g < 32768) z1[g] = zero;
            else if (g < 98304)  z2[g - 32768] = zero;
            else if (g < 229376) z3[g - 98304] = zero;
            else if (g < 294912) zc1[g - 229376] = zero;
            else if (g < 425984) zc2[g - 294912] = zero;
            else                 zc3[g - 425984] = zero;
        }
    }
    // pre-barrier: tick[] final -> everyone computes nxcd / nbx
    gbar(fullc, invdone, 1, 0, elected, nxcd, 0);
    if (tid == 0) {
        nxcd = 0;
        for (int i = 0; i < 8; ++i)
            nxcd += (__hip_atomic_load(&tick[i * 32], __ATOMIC_RELAXED,
                                       __HIP_MEMORY_SCOPE_AGENT) > 0);
        if (nxcd == 0) nxcd = 1;
        uint nb = __hip_atomic_load(&tick[shmeta[2] * 32], __ATOMIC_RELAXED,
                                    __HIP_MEMORY_SCOPE_AGENT);
        shmeta[1] = (int)(nb ? nb : 1);
    }
    // publish pack outputs + zeros to IF (elected wbl2 per XCD); readers
    // everywhere first-touch them fresh afterwards.
    gbar(fullc, invdone, 2, 1, elected, nxcd, 1);

    const int rank = shmeta[0];
    const int nbx  = shmeta[1];
    const int xcd  = shmeta[2];
    uint* myx = &xctr[xcd * 32];

    // ================= diagonal ConvLSTM schedule (XCD-local) ==============
    // per-XCD tile list (112): [0,64) L3, [64,96) L2, [96,112) L1.
    for (int d = 0; d < T + 2; ++d) {
        const int t3 = d - 2, t2 = d - 1, t1 = d;
        for (int idx = rank; idx < 112; idx += nbx) {
            if (idx < 64) {
                if ((unsigned)t3 < (unsigned)T) {
                    int bb = idx >> 4, sub = idx & 15;
                    int fblk = sub & 7, lblk = sub >> 3;
                    int b = xcd + bb * 8;
                    int tile = ((b * 2 + lblk) << 3) | fblk;
                    const ushort* h3o = (t3 & 1) ? A.h3b : A.h3a;
                    ushort*       h3n = (t3 & 1) ? A.h3a : A.h3b;
                    do_tile<128, 12, 36, 256, 3, 0, 7>(slab, A.zbuf, tile, L,
                            A.h2seq + (long)t3 * L * F2, (long)T * L * F2,
                            h3o, h3n, A.wp3, A.b3, A.c3s,
                            (t3 == T - 1) ? (void*)A.h3bn : nullptr,
                            (long)L * F3, 1, A.g3, A.be3, A.m3, A.v3);
                }
            } else if (idx < 96) {
                if ((unsigned)t2 < (unsigned)T) {
                    int j = idx - 64;
                    int bb = j >> 3, sub = j & 7;
                    int fblk = sub & 3, lblk = sub >> 2;
                    int b = xcd + bb * 8;
                    int tile = ((b * 2 + lblk) << 2) | fblk;
                    const ushort* h2o = (t2 & 1) ? A.h2b : A.h2a;
                    ushort*       h2n = (t2 & 1) ? A.h2a : A.h2b;
                    do_tile<64, 6, 18, 128, 2, 0, 7>(slab, A.zbuf, tile, L,
                            A.h1seq + (long)t2 * L * F1, (long)T * L * F1,
                            h2o, h2n, A.wp2, A.b2, A.c2s,
                            A.h2seq + (long)t2 * L * F2, (long)T * L * F2, 0,
                            A.g2, A.be2, A.m2, A.v2);
                }
            } else {
                if ((unsigned)t1 < (unsigned)T) {
                    int j = idx - 96;
                    int bb = j >> 2, sub = j & 3;
                    int fblk = sub & 1, lblk = sub >> 1;
                    int b = xcd + bb * 8;
                    int tile = ((b * 2 + lblk) << 1) | fblk;
                    const ushort* h1o = (t1 & 1) ? A.h1b : A.h1a;
                    ushort*       h1n = (t1 & 1) ? A.h1a : A.h1b;
                    do_tile<32, 1, 7, 64, 1, 1, 3>(slab, A.zbuf, tile, L,
                            A.x + (long)t1 * L, (long)T * L,
                            h1o, h1n, A.wp1, A.b1, A.c1s,
                            A.h1seq + (long)t1 * L * F1, (long)T * L * F1, 0,
                            A.g1, A.be1, A.m1, A.v1);
                }
            }
        }
        // per-XCD barrier: stores are in this XCD's L2 (the coherence point
        // for all readers of this data) -> no flush, no inv.
        __syncthreads();
        if (tid == 0) {
            __hip_atomic_fetch_add(myx, 1u, __ATOMIC_RELAXED, __HIP_MEMORY_SCOPE_AGENT);
            spin_until(myx, (uint)(d + 1) * (uint)nbx);
        }
        asm volatile("" ::: "memory");
        __syncthreads();
    }
    // publish h3bn (cross-XCD) for the dense head
    gbar(fullc, invdone, 3, 2, elected, nxcd, 1);

    // ================= dense head ==========================================
    // D1 partial: KT=256, N-tile 256; 512 jobs == 512 blocks.
    {
        __syncthreads();
        float* A_s = (float*)slab;                 // [256][33] = 33.8 KB
        const int n0 = (bid & 3) * 256;
        const int kt = bid >> 2;                   // 0..127
        const int k0 = kt * 256;
        for (int idx = tid; idx < 256 * 32; idx += 256) {
            int m = idx >> 8, k = idx & 255;
            A_s[k * 33 + m] = A.h3bn[(long)m * 32768 + k0 + k];
        }
        __syncthreads();

        const int nq = (tid & 63) * 4;
        const int mg = tid >> 6;
        f32x4 acc[8];
#pragma unroll
        for (int i = 0; i < 8; ++i) acc[i] = (f32x4)(0.f);

        const float* wp0 = &A.D1[(long)k0 * 1024 + n0 + nq];
#define LDW(kk) (*(const f32x4*)(wp0 + (long)(kk) * 1024))
#define DPF(kk, W) do {                                      \
        const float* ap = &A_s[(kk) * 33 + mg * 8];          \
        acc[0] += ap[0] * (W); acc[1] += ap[1] * (W);        \
        acc[2] += ap[2] * (W); acc[3] += ap[3] * (W);        \
        acc[4] += ap[4] * (W); acc[5] += ap[5] * (W);        \
        acc[6] += ap[6] * (W); acc[7] += ap[7] * (W);        \
    } while (0)
        f32x4 wa = LDW(0), wb = LDW(1), wc = LDW(2), wd = LDW(3);
        for (int k = 0; k < 252; k += 4) {
            DPF(k + 0, wa); wa = LDW(k + 4);
            DPF(k + 1, wb); wb = LDW(k + 5);
            DPF(k + 2, wc); wc = LDW(k + 6);
            DPF(k + 3, wd); wd = LDW(k + 7);
        }
        DPF(252, wa); DPF(253, wb); DPF(254, wc); DPF(255, wd);
#undef LDW
#undef DPF
#pragma unroll
        for (int mm = 0; mm < 8; ++mm)
            *(f32x4*)&A.partials[((long)kt * 32 + mg * 8 + mm) * 1024 + n0 + nq] = acc[mm];
    }
    gbar(fullc, invdone, 4, 3, elected, nxcd, 1);

    // reduce + relu -> a1 [32,1024] (partials own region, first-touch reads)
    if (bid < 128) {
        int idx = bid * 256 + tid;
        int m = idx >> 10, n = idx & 1023;
        float s = A.db1[n];
#pragma unroll 4
        for (int j = 0; j < 128; ++j)
            s += A.partials[((long)j * 32 + m) * 1024 + n];
        A.a1[idx] = fmaxf(s, 0.f);
    }
    gbar(fullc, invdone, 5, 4, elected, nxcd, 1);

    // D2 + relu -> a2 [32,512]
    if (bid < 64) {
        float* A_s = (float*)slab;                 // [1024]
        int m = bid >> 1;
        int n = ((bid & 1) << 8) + tid;
        for (int k = tid; k < 1024; k += 256) A_s[k] = A.a1[(long)m * 1024 + k];
        __syncthreads();
        float acc = 0.f;
#pragma unroll 8
        for (int k = 0; k < 1024; ++k)
            acc += A_s[k] * A.D2[(long)k * 512 + n];
        A.a2[(long)m * 512 + n] = fmaxf(acc + A.db2[n], 0.f);
    }
    gbar(fullc, invdone, 6, 5, elected, nxcd, 1);

    // D3 + softmax -> out [32,5]
    if (bid < 32 && tid < 64) {
        float part[5] = {0.f, 0.f, 0.f, 0.f, 0.f};
        for (int k = tid; k < 512; k += 64) {
            float a = A.a2[bid * 512 + k];
#pragma unroll
            for (int j = 0; j < 5; ++j) part[j] += a * A.D3[k * 5 + j];
        }
        float lg[5];
#pragma unroll
        for (int j = 0; j < 5; ++j) {
            float v = part[j];
            for (int off = 32; off; off >>= 1) v += __shfl_down(v, off);
            lg[j] = v + A.db3[j];
        }
        if (tid == 0) {
            float mx = lg[0];
#pragma unroll
            for (int j = 1; j < 5; ++j) mx = fmaxf(mx, lg[j]);
            float s = 0.f, e[5];
#pragma unroll
            for (int j = 0; j < 5; ++j) { e[j] = expf(lg[j] - mx); s += e[j]; }
#pragma unroll
            for (int j = 0; j < 5; ++j) A.out[bid * 5 + j] = e[j] / s;
        }
    }
}

extern "C" void kernel_launch(void* const* d_in, const int* in_sizes, int n_in,
                              void* d_out, int out_size, void* d_ws, size_t ws_size,
                              hipStream_t stream)
{
    const int B = 32, T = 32, L = 128;
    const int F1 = 64, F2 = 128, F3 = 256;
    (void)in_sizes; (void)n_in; (void)out_size; (void)ws_size;

    // ---- workspace layout (~110 MB) ----
    char* p = (char*)d_ws;
    ushort* h1seq = (ushort*)p; p += (size_t)B * T * L * F1 * 2;   // 16.8 MB
    ushort* h2seq = (ushort*)p; p += (size_t)B * T * L * F2 * 2;   // 33.6 MB
    ushort* h1a = (ushort*)p; p += (size_t)B * L * F1 * 2;
    ushort* h1b = (ushort*)p; p += (size_t)B * L * F1 * 2;
    ushort* h2a = (ushort*)p; p += (size_t)B * L * F2 * 2;
    ushort* h2b = (ushort*)p; p += (size_t)B * L * F2 * 2;
    ushort* h3a = (ushort*)p; p += (size_t)B * L * F3 * 2;
    ushort* h3b = (ushort*)p; p += (size_t)B * L * F3 * 2;
    float*  c1s = (float*)p; p += (size_t)B * L * F1 * 4;          // 1 MB
    float*  c2s = (float*)p; p += (size_t)B * L * F2 * 4;          // 2 MB
    float*  c3s = (float*)p; p += (size_t)B * L * F3 * 4;          // 4 MB
    float*  h3bn = (float*)p; p += (size_t)B * L * F3 * 4;
    uint4*  wp1 = (uint4*)p; p += (size_t)2 * 7 * 512 * 16;
    uint4*  wp2 = (uint4*)p; p += (size_t)4 * 18 * 512 * 16;
    uint4*  wp3 = (uint4*)p; p += (size_t)8 * 36 * 512 * 16;
    float*  a1 = (float*)p; p += (size_t)B * 1024 * 4;
    float*  a2 = (float*)p; p += (size_t)B * 512 * 4;
    ushort* zbuf = (ushort*)p; p += 128;
    uint*   ctr = (uint*)p; p += 4096;
    float*  partials = (float*)p; p += (size_t)128 * 32 * 1024 * 4;  // 16.8 MB

    FusedArgs A;
    A.x   = (const float*)d_in[0];
    A.Wx1 = (const float*)d_in[1];  A.Wh1 = (const float*)d_in[2];
    A.b1  = (const float*)d_in[3];
    A.Wx2 = (const float*)d_in[4];  A.Wh2 = (const float*)d_in[5];
    A.b2  = (const float*)d_in[6];
    A.Wx3 = (const float*)d_in[7];  A.Wh3 = (const float*)d_in[8];
    A.b3  = (const float*)d_in[9];
    A.g1 = (const float*)d_in[10]; A.be1 = (const float*)d_in[11];
    A.m1 = (const float*)d_in[12]; A.v1  = (const float*)d_in[13];
    A.g2 = (const float*)d_in[14]; A.be2 = (const float*)d_in[15];
    A.m2 = (const float*)d_in[16]; A.v2  = (const float*)d_in[17];
    A.g3 = (const float*)d_in[18]; A.be3 = (const float*)d_in[19];
    A.m3 = (const float*)d_in[20]; A.v3  = (const float*)d_in[21];
    A.D1 = (const float*)d_in[22]; A.db1 = (const float*)d_in[23];
    A.D2 = (const float*)d_in[24]; A.db2 = (const float*)d_in[25];
    A.D3 = (const float*)d_in[26]; A.db3 = (const float*)d_in[27];
    A.h1seq = h1seq; A.h2seq = h2seq;
    A.h1a = h1a; A.h1b = h1b; A.h2a = h2a; A.h2b = h2b;
    A.h3a = h3a; A.h3b = h3b;
    A.c1s = c1s; A.c2s = c2s; A.c3s = c3s;
    A.h3bn = h3bn; A.a1 = a1; A.a2 = a2; A.partials = partials;
    A.out = (float*)d_out;
    A.wp1 = wp1; A.wp2 = wp2; A.wp3 = wp3;
    A.zbuf = zbuf; A.ctr = ctr;

    hipMemsetAsync(zbuf, 0, 128, stream);
    hipMemsetAsync(ctr, 0, 16384, stream);
    fused<<<NB, 256, 0, stream>>>(A);
}